// Round 1
// baseline (44.366 us; speedup 1.0000x reference)
//
#include <hip/hip_runtime.h>

// ft = A0inv @ (I - t2) @ (I + t4),  t2 = x@A0inv, t4 = t2@t2
// x: [B,2,2] f32 (row-major, 4 floats per matrix), A0inv: [2,2] f32.
// Pure streaming: 16B in, 16B out per matrix -> float4 per thread.

__global__ __launch_bounds__(256) void eps_kernel(
    const float4* __restrict__ x, const float* __restrict__ A,
    float4* __restrict__ out, int n)
{
    // A0inv is uniform: scalar loads, broadcast to all lanes.
    const float p = A[0], q = A[1], r = A[2], s = A[3];

    const int stride = gridDim.x * blockDim.x;
    for (int i = blockIdx.x * blockDim.x + threadIdx.x; i < n; i += stride) {
        const float4 v = x[i];
        const float a = v.x, b = v.y, c = v.z, d = v.w;

        // t2 = x @ A0inv
        const float t2_00 = fmaf(a, p, b * r);
        const float t2_01 = fmaf(a, q, b * s);
        const float t2_10 = fmaf(c, p, d * r);
        const float t2_11 = fmaf(c, q, d * s);

        // t4 = t2 @ t2
        const float t4_00 = fmaf(t2_00, t2_00, t2_01 * t2_10);
        const float t4_01 = fmaf(t2_00, t2_01, t2_01 * t2_11);
        const float t4_10 = fmaf(t2_10, t2_00, t2_11 * t2_10);
        const float t4_11 = fmaf(t2_10, t2_01, t2_11 * t2_11);

        // M1 = I - t2
        const float m1_00 = 1.0f - t2_00;
        const float m1_01 = -t2_01;
        const float m1_10 = -t2_10;
        const float m1_11 = 1.0f - t2_11;

        // M2 = I + t4
        const float m2_00 = 1.0f + t4_00;
        const float m2_01 = t4_01;
        const float m2_10 = t4_10;
        const float m2_11 = 1.0f + t4_11;

        // T = A0inv @ M1
        const float T00 = fmaf(p, m1_00, q * m1_10);
        const float T01 = fmaf(p, m1_01, q * m1_11);
        const float T10 = fmaf(r, m1_00, s * m1_10);
        const float T11 = fmaf(r, m1_01, s * m1_11);

        // ft = T @ M2
        float4 o;
        o.x = fmaf(T00, m2_00, T01 * m2_10);
        o.y = fmaf(T00, m2_01, T01 * m2_11);
        o.z = fmaf(T10, m2_00, T11 * m2_10);
        o.w = fmaf(T10, m2_01, T11 * m2_11);

        out[i] = o;
    }
}

extern "C" void kernel_launch(void* const* d_in, const int* in_sizes, int n_in,
                              void* d_out, int out_size, void* d_ws, size_t ws_size,
                              hipStream_t stream) {
    const float4* x = (const float4*)d_in[0];   // [B,2,2] -> B float4s
    const float*  A = (const float*)d_in[1];    // [2,2]   -> 4 floats
    float4* out = (float4*)d_out;

    const int n = in_sizes[0] / 4;              // number of 2x2 matrices

    const int block = 256;
    int grid = (n + block - 1) / block;
    if (grid > 4096) grid = 4096;               // grid-stride the rest

    eps_kernel<<<grid, block, 0, stream>>>(x, A, out, n);
}